// Round 4
// baseline (94.846 us; speedup 1.0000x reference)
//
#include <hip/hip_runtime.h>
#include <hip/hip_fp16.h>
#include <math.h>

#define HH   128
#define WW   160
#define HWN  (HH*WW)      // 20480
#define NCF  32           // feature channels
#define NCD  8            // deps channels
#define ND   32           // depths
#define NV   3            // views
#define LAMBF 1.5f
#define SNAPF 2e-4f       // pure-roundoff fraction snap (min real frac ~0.016)

#define BX   40           // pixels per block (4 blocks per image row)
#define FPAD 40           // LF row pad in halves: 80B = 16B-aligned, bank-stride 20

#define H2OF(u, k) (((const __half2*)&(u))[k])

// ---------------------------------------------------------------------------
// Single fused kernel. Block = one 40-px segment of one image row.
// Verified on this data: warp is a pure horizontal shift (rot == I, ty == 0)
// so py == y after roundoff-snap -> every bilinear footprint lives in source
// row y. Stage all 3 views' feat rows (fp16 [x][c], padded) + deps rows in
// LDS; the warp becomes a 2-tap x-interp from LDS. Thread = (depth, px-slot),
// owns all 32+8 channels -> no shfl, no workspace, no prep kernel.
// Generic fallback (exec-masked, not taken here): global 4-corner f32 gather.
// grid = 128 rows * 4 = 512 blocks, 256 threads.
// ---------------------------------------------------------------------------
__global__ __launch_bounds__(256) void fused_k(
    const float* __restrict__ feat,   // (V,32,H,W) f32
    const float* __restrict__ deps,   // (V,8,H,W)  f32
    const float* __restrict__ proj,   // (V,4,4)
    const float* __restrict__ dvals,  // (D,H,W)
    const float* __restrict__ regw,   // 40
    float* __restrict__ out)
{
    __shared__ __align__(16) __half LF [NV][WW][FPAD]; // 38400 B
    __shared__ __align__(16) __half LDP[NV][WW][NCD];  //  7680 B
    __shared__ float CL[ND][BX+4];                     //  5632 B
    __shared__ float DV[ND][BX+4];                     //  5632 B
    __shared__ float smax[BX], sisum[BX];              //   320 B  => 57.7 KB

    const int t   = threadIdx.x;
    const int y   = blockIdx.x >> 2;
    const int x0  = (blockIdx.x & 3) * BX;
    const int row = y * WW;

    // ---------- relative projections (uniform math, every thread) ----------
    float PR[2][12];
    {
        float M00=proj[0], M01=proj[1], M02=proj[2],  m0=proj[3];
        float M10=proj[4], M11=proj[5], M12=proj[6],  m1=proj[7];
        float M20=proj[8], M21=proj[9], M22=proj[10], m2=proj[11];
        float c00= (M11*M22-M12*M21);
        float c01=-(M10*M22-M12*M20);
        float c02= (M10*M21-M11*M20);
        float det=M00*c00+M01*c01+M02*c02;
        float id=1.f/det;
        float i00=c00*id, i01=-(M01*M22-M02*M21)*id, i02= (M01*M12-M02*M11)*id;
        float i10=c01*id, i11= (M00*M22-M02*M20)*id, i12=-(M00*M12-M02*M10)*id;
        float i20=c02*id, i21=-(M00*M21-M01*M20)*id, i22= (M00*M11-M01*M10)*id;
        float t0=-(i00*m0+i01*m1+i02*m2);
        float t1=-(i10*m0+i11*m1+i12*m2);
        float t2=-(i20*m0+i21*m1+i22*m2);
        #pragma unroll
        for (int v = 0; v < 2; v++) {
            const float* S = proj + (v+1)*16;
            float s00=S[0], s01=S[1], s02=S[2],  st0=S[3];
            float s10=S[4], s11=S[5], s12=S[6],  st1=S[7];
            float s20=S[8], s21=S[9], s22=S[10], st2=S[11];
            PR[v][0]=s00*i00+s01*i10+s02*i20;
            PR[v][1]=s00*i01+s01*i11+s02*i21;
            PR[v][2]=s00*i02+s01*i12+s02*i22;
            PR[v][3]=s10*i00+s11*i10+s12*i20;
            PR[v][4]=s10*i01+s11*i11+s12*i21;
            PR[v][5]=s10*i02+s11*i12+s12*i22;
            PR[v][6]=s20*i00+s21*i10+s22*i20;
            PR[v][7]=s20*i01+s21*i11+s22*i21;
            PR[v][8]=s20*i02+s21*i12+s22*i22;
            PR[v][9] =s00*t0+s01*t1+s02*t2+st0;
            PR[v][10]=s10*t0+s11*t1+s12*t2+st1;
            PR[v][11]=s20*t0+s21*t1+s22*t2+st2;
        }
    }

    // ---------- stage the 3 views' rows into LDS (f32 -> fp16) ----------
    // 120 planes (96 feat + 24 deps) x 160 px = 19200 scalar loads, 75/thread.
    // Lanes sweep x (coalesced global; LDS store stride 80B -> <=4-way bank).
    for (int idx = t; idx < (NV*NCF + NV*NCD)*WW; idx += 256) {
        int plane = idx / WW;
        int xx    = idx - plane*WW;
        if (plane < NV*NCF) {
            LF[plane>>5][xx][plane&31] =
                __float2half_rn(feat[(size_t)plane*HWN + row + xx]);
        } else {
            int p2 = plane - NV*NCF;
            LDP[p2>>3][xx][p2&7] =
                __float2half_rn(deps[(size_t)p2*HWN + row + xx]);
        }
    }

    // ---------- per-thread channel weights (uniform) ----------
    __half2 wca2[16], nwcb2[16], dca2[4], ndcb2[4];
    #pragma unroll
    for (int k = 0; k < 16; k++) {
        float wa = regw[2*k], wb = regw[2*k+1];
        wca2[k]  = __floats2half2_rn( wa*(1.f/3.f),  wb*(1.f/3.f));
        nwcb2[k] = __floats2half2_rn(-wa*(1.f/9.f), -wb*(1.f/9.f));
    }
    #pragma unroll
    for (int k = 0; k < 4; k++) {
        float wa = regw[NCF+2*k], wb = regw[NCF+2*k+1];
        dca2[k]  = __floats2half2_rn( wa*(1.f/3.f),  wb*(1.f/3.f));
        ndcb2[k] = __floats2half2_rn(-wa*(1.f/9.f), -wb*(1.f/9.f));
    }

    const int ds = t >> 3;          // depth 0..31
    const int xs = t & 7;           // px slot
    const float fyv = (float)y;
    float AX[2],BXx[2],AY[2],BY[2],AZ[2],BZ[2],Tx[2],Ty[2],Tz[2];
    #pragma unroll
    for (int v = 0; v < 2; v++) {
        AX[v]=PR[v][0]; BXx[v]=PR[v][1]*fyv+PR[v][2];
        AY[v]=PR[v][3]; BY[v] =PR[v][4]*fyv+PR[v][5];
        AZ[v]=PR[v][6]; BZ[v] =PR[v][7]*fyv+PR[v][8];
        Tx[v]=PR[v][9]; Ty[v]=PR[v][10]; Tz[v]=PR[v][11];
    }

    __syncthreads();

    // ---------- compute: 5 (x,d) pairs per thread ----------
    #pragma unroll 1
    for (int i = 0; i < 5; i++) {
        const int xl = xs + 8*i;        // 0..39
        const int x  = x0 + xl;
        const float fxv = (float)x;
        const float dvv = dvals[ds*HWN + row + x];
        DV[ds][xl] = dvv;

        // init sums from ref view (view 0)
        __half2 s2[16], q2[16], sd2[4], qd2[4];
        {
            const __half* RF = &LF[0][x][0];
            uint4 R0=*(const uint4*)(RF),    R1=*(const uint4*)(RF+8),
                  R2=*(const uint4*)(RF+16), R3=*(const uint4*)(RF+24);
            #pragma unroll
            for (int k = 0; k < 4; k++) {
                __half2 r;
                r=H2OF(R0,k); s2[k]   =r; q2[k]   =__hmul2(r,r);
                r=H2OF(R1,k); s2[4+k] =r; q2[4+k] =__hmul2(r,r);
                r=H2OF(R2,k); s2[8+k] =r; q2[8+k] =__hmul2(r,r);
                r=H2OF(R3,k); s2[12+k]=r; q2[12+k]=__hmul2(r,r);
            }
            uint4 RD=*(const uint4*)&LDP[0][x][0];
            #pragma unroll
            for (int k = 0; k < 4; k++) {
                __half2 r=H2OF(RD,k); sd2[k]=r; qd2[k]=__hmul2(r,r);
            }
        }

        #pragma unroll
        for (int v = 0; v < 2; v++) {
            float RZv = AZ[v]*fxv + BZ[v];
            float pz  = RZv*dvv + Tz[v];
            float iz  = __builtin_amdgcn_rcpf(pz);
            float px  = (AX[v]*fxv + BXx[v])*dvv + Tx[v];  px *= iz;
            float py  = (AY[v]*fxv + BY[v]) *dvv + Ty[v];  py *= iz;
            float x0f = floorf(px), y0f = floorf(py);
            float wx = px - x0f, wy = py - y0f;
            if (wx < SNAPF)            wx = 0.f;
            else if (wx > 1.f-SNAPF) { wx = 0.f; x0f += 1.f; }
            if (wy < SNAPF)            wy = 0.f;
            else if (wy > 1.f-SNAPF) { wy = 0.f; y0f += 1.f; }
            int x0i=(int)x0f, y0i=(int)y0f;
            float omx = 1.f - wx;
            int xb = min(max(x0i,0), WW-2);
            float wx0 = (x0i==xb)?omx:((x0i==xb-1)?wx :0.f);
            float wx1 = (x0i==xb)?wx :((x0i==xb+1)?omx:0.f);

            if (wy == 0.f && y0i == y) {
                // fast: 2-tap x-interp from the staged row
                __half2 W0 = __floats2half2_rn(wx0, wx0);
                __half2 W1 = __floats2half2_rn(wx1, wx1);
                const __half* F0 = &LF[1+v][xb][0];
                uint4 Ta0=*(const uint4*)(F0),         Ta1=*(const uint4*)(F0+8),
                      Ta2=*(const uint4*)(F0+16),      Ta3=*(const uint4*)(F0+24);
                uint4 Tb0=*(const uint4*)(F0+FPAD),    Tb1=*(const uint4*)(F0+FPAD+8),
                      Tb2=*(const uint4*)(F0+FPAD+16), Tb3=*(const uint4*)(F0+FPAD+24);
                #pragma unroll
                for (int k = 0; k < 4; k++) {
                    __half2 wv;
                    wv=__hmul2(H2OF(Ta0,k),W0); wv=__hfma2(H2OF(Tb0,k),W1,wv);
                    s2[k]    =__hadd2(s2[k],wv);     q2[k]    =__hfma2(wv,wv,q2[k]);
                    wv=__hmul2(H2OF(Ta1,k),W0); wv=__hfma2(H2OF(Tb1,k),W1,wv);
                    s2[4+k]  =__hadd2(s2[4+k],wv);   q2[4+k]  =__hfma2(wv,wv,q2[4+k]);
                    wv=__hmul2(H2OF(Ta2,k),W0); wv=__hfma2(H2OF(Tb2,k),W1,wv);
                    s2[8+k]  =__hadd2(s2[8+k],wv);   q2[8+k]  =__hfma2(wv,wv,q2[8+k]);
                    wv=__hmul2(H2OF(Ta3,k),W0); wv=__hfma2(H2OF(Tb3,k),W1,wv);
                    s2[12+k] =__hadd2(s2[12+k],wv);  q2[12+k] =__hfma2(wv,wv,q2[12+k]);
                }
                const __half* D0 = &LDP[1+v][xb][0];
                uint4 Da=*(const uint4*)(D0);
                uint4 Db=*(const uint4*)(D0+NCD);
                #pragma unroll
                for (int k = 0; k < 4; k++) {
                    __half2 wv=__hmul2(H2OF(Da,k),W0); wv=__hfma2(H2OF(Db,k),W1,wv);
                    sd2[k]=__hadd2(sd2[k],wv); qd2[k]=__hfma2(wv,wv,qd2[k]);
                }
            } else if (!(wy == 0.f && (y0i < 0 || y0i > HH-1))) {
                // generic global 4-corner fallback (never taken on this data);
                // the (wy==0 && y-row fully OOB) case contributes exactly 0 and
                // is skipped entirely by the condition above.
                float omy = 1.f - wy;
                int yb = min(max(y0i,0), HH-2);
                float wy0 = (y0i==yb)?omy:((y0i==yb-1)?wy :0.f);
                float wy1 = (y0i==yb)?wy :((y0i==yb+1)?omy:0.f);
                float w00=wx0*wy0, w10=wx1*wy0, w01=wx0*wy1, w11=wx1*wy1;
                const float* fb = feat + (size_t)(1+v)*NCF*HWN + yb*WW + xb;
                #pragma unroll
                for (int k = 0; k < 16; k++) {
                    const float* p0 = fb + (size_t)(2*k)*HWN;
                    const float* p1 = fb + (size_t)(2*k+1)*HWN;
                    float va = w00*p0[0]+w10*p0[1]+w01*p0[WW]+w11*p0[WW+1];
                    float vb = w00*p1[0]+w10*p1[1]+w01*p1[WW]+w11*p1[WW+1];
                    __half2 wv = __floats2half2_rn(va, vb);
                    s2[k]=__hadd2(s2[k],wv); q2[k]=__hfma2(wv,wv,q2[k]);
                }
                const float* db = deps + (size_t)(1+v)*NCD*HWN + yb*WW + xb;
                #pragma unroll
                for (int k = 0; k < 4; k++) {
                    const float* p0 = db + (size_t)(2*k)*HWN;
                    const float* p1 = db + (size_t)(2*k+1)*HWN;
                    float va = w00*p0[0]+w10*p0[1]+w01*p0[WW]+w11*p0[WW+1];
                    float vb = w00*p1[0]+w10*p1[1]+w01*p1[WW]+w11*p1[WW+1];
                    __half2 wv = __floats2half2_rn(va, vb);
                    sd2[k]=__hadd2(sd2[k],wv); qd2[k]=__hfma2(wv,wv,qd2[k]);
                }
            }
        }

        // cost dot: variance = q/3 - (s/3)^2, grouped in 8-ch f32 partials
        float costf = 0.f;
        #pragma unroll
        for (int g = 0; g < 4; g++) {
            __half2 acc = __hmul2(q2[4*g], wca2[4*g]);
            acc = __hfma2(__hmul2(s2[4*g],s2[4*g]), nwcb2[4*g], acc);
            #pragma unroll
            for (int k = 1; k < 4; k++) {
                acc = __hfma2(q2[4*g+k], wca2[4*g+k], acc);
                acc = __hfma2(__hmul2(s2[4*g+k],s2[4*g+k]), nwcb2[4*g+k], acc);
            }
            float2 af = __half22float2(acc);
            costf += af.x + af.y;
        }
        {
            __half2 acc = __hmul2(qd2[0], dca2[0]);
            acc = __hfma2(__hmul2(sd2[0],sd2[0]), ndcb2[0], acc);
            #pragma unroll
            for (int k = 1; k < 4; k++) {
                acc = __hfma2(qd2[k], dca2[k], acc);
                acc = __hfma2(__hmul2(sd2[k],sd2[k]), ndcb2[k], acc);
            }
            float2 af = __half22float2(acc);
            costf += af.x + af.y;
        }
        CL[ds][xl] = costf;
    }
    __syncthreads();

    // ---------- softmax + moments (one thread per pixel) ----------
    if (t < BX) {
        float m = -1e30f;
        #pragma unroll
        for (int d = 0; d < ND; d++) m = fmaxf(m, CL[d][t]);
        float sum=0.f, pd=0.f, pd2=0.f;
        #pragma unroll
        for (int d = 0; d < ND; d++) {
            float e   = __expf(CL[d][t] - m);
            float dvv = DV[d][t];
            sum += e;
            pd   = fmaf(e, dvv, pd);
            pd2  = fmaf(e, dvv*dvv, pd2);
        }
        float isum  = 1.f / sum;
        float depth = pd * isum;
        float sv    = pd2 * isum - depth*depth;
        float ev    = LAMBF * sqrtf(fmaxf(sv, 0.f));
        smax[t]  = m;
        sisum[t] = isum;
        const int pix = row + x0 + t;
        out[pix]       = depth;
        out[HWN + pix] = ev;
    }
    __syncthreads();

    // ---------- probability volume ----------
    #pragma unroll
    for (int i = 0; i < 5; i++) {
        const int xl  = xs + 8*i;
        const int pix = row + x0 + xl;
        out[2*HWN + ds*HWN + pix] = __expf(CL[ds][xl] - smax[xl]) * sisum[xl];
    }
}

// ---------------------------------------------------------------------------
extern "C" void kernel_launch(void* const* d_in, const int* in_sizes, int n_in,
                              void* d_out, int out_size, void* d_ws, size_t ws_size,
                              hipStream_t stream) {
    const float* features = (const float*)d_in[0];   // (V,1,32,H,W)
    const float* deps     = (const float*)d_in[1];   // (V,1,8,H,W)
    const float* proj     = (const float*)d_in[2];   // (1,V,4,4)
    const float* dvals    = (const float*)d_in[3];   // (1,D,H,W)
    const float* regw     = (const float*)d_in[4];   // (1,40)
    (void)d_ws; (void)ws_size;                       // workspace unused now

    fused_k<<<HH*4, 256, 0, stream>>>(features, deps, proj, dvals, regw,
                                      (float*)d_out);
}

// Round 5
// 88.484 us; speedup vs baseline: 1.0719x; 1.0719x over previous
//
#include <hip/hip_runtime.h>
#include <hip/hip_fp16.h>
#include <math.h>

#define HH   128
#define WW   160
#define HWN  (HH*WW)      // 20480
#define NCF  32           // feature channels
#define NCD  8            // deps channels
#define ND   32           // depths
#define NV   3            // views
#define LAMBF 1.5f
#define SNAPF 2e-4f       // pure-roundoff fraction snap (min real frac ~0.016)

// ---------------------------------------------------------------------------
// Prep: transpose (V,CH,H,W) f32 -> (V,HW,CH) fp16 channel-last.
// 3840 tiny blocks (verified fastest geometry; fully parallel, ~2 mem ops/thread).
// block(0,0,0)/thread0 also computes proj_v @ inv(proj_ref) -> projw[24].
// ---------------------------------------------------------------------------
template <int CH>
__device__ void transpose_tile(const float* __restrict__ src, __half* __restrict__ dst,
                               float (*lds)[33], int tid) {
    for (int i = tid; i < CH*8; i += 256) {
        int c = i >> 3, xg = (i & 7) << 2;
        *(float4*)&lds[c][xg] = *(const float4*)(src + c*HWN + xg);
    }
    __syncthreads();
    for (int i = tid; i < 32*(CH/4); i += 256) {
        int xl = i / (CH/4), c4 = (i % (CH/4)) * 4;
        __half2 h0 = __floats2half2_rn(lds[c4][xl],   lds[c4+1][xl]);
        __half2 h1 = __floats2half2_rn(lds[c4+2][xl], lds[c4+3][xl]);
        uint2 u; u.x = *(unsigned*)&h0; u.y = *(unsigned*)&h1;
        *(uint2*)(dst + xl*CH + c4) = u;
    }
}

__global__ __launch_bounds__(256) void prep_k(const float* __restrict__ feat,
                                              const float* __restrict__ deps,
                                              const float* __restrict__ proj,
                                              __half* __restrict__ featH,
                                              __half* __restrict__ depsH,
                                              float* __restrict__ projw) {
    if (blockIdx.x == 0 && blockIdx.y == 0 && blockIdx.z == 0 && threadIdx.x == 0) {
        float M00 = proj[0], M01 = proj[1], M02 = proj[2],  m0 = proj[3];
        float M10 = proj[4], M11 = proj[5], M12 = proj[6],  m1 = proj[7];
        float M20 = proj[8], M21 = proj[9], M22 = proj[10], m2 = proj[11];
        float c00 =  (M11*M22 - M12*M21);
        float c01 = -(M10*M22 - M12*M20);
        float c02 =  (M10*M21 - M11*M20);
        float det = M00*c00 + M01*c01 + M02*c02;
        float id  = 1.f / det;
        float i00 = c00*id, i01 = -(M01*M22 - M02*M21)*id, i02 =  (M01*M12 - M02*M11)*id;
        float i10 = c01*id, i11 =  (M00*M22 - M02*M20)*id, i12 = -(M00*M12 - M02*M10)*id;
        float i20 = c02*id, i21 = -(M00*M21 - M01*M20)*id, i22 =  (M00*M11 - M01*M10)*id;
        float t0 = -(i00*m0 + i01*m1 + i02*m2);
        float t1 = -(i10*m0 + i11*m1 + i12*m2);
        float t2 = -(i20*m0 + i21*m1 + i22*m2);
        #pragma unroll
        for (int v = 1; v < NV; v++) {
            const float* S = proj + v*16;
            float s00 = S[0], s01 = S[1], s02 = S[2],  st0 = S[3];
            float s10 = S[4], s11 = S[5], s12 = S[6],  st1 = S[7];
            float s20 = S[8], s21 = S[9], s22 = S[10], st2 = S[11];
            float* o = projw + (v-1)*12;
            o[0] = s00*i00 + s01*i10 + s02*i20;
            o[1] = s00*i01 + s01*i11 + s02*i21;
            o[2] = s00*i02 + s01*i12 + s02*i22;
            o[3] = s10*i00 + s11*i10 + s12*i20;
            o[4] = s10*i01 + s11*i11 + s12*i21;
            o[5] = s10*i02 + s11*i12 + s12*i22;
            o[6] = s20*i00 + s21*i10 + s22*i20;
            o[7] = s20*i01 + s21*i11 + s22*i21;
            o[8] = s20*i02 + s21*i12 + s22*i22;
            o[9]  = s00*t0 + s01*t1 + s02*t2 + st0;
            o[10] = s10*t0 + s11*t1 + s12*t2 + st1;
            o[11] = s20*t0 + s11*t1*0.f + s21*t1 + s22*t2 + st2;
        }
    }

    __shared__ float lds[NCF][33];
    const int z  = blockIdx.z;
    const int xb = blockIdx.x * 32;
    const int y  = blockIdx.y;
    if (z < NV) {
        transpose_tile<NCF>(feat + (size_t)(z*NCF)*HWN + y*WW + xb,
                            featH + (size_t)(z*HWN + y*WW + xb) * NCF,
                            lds, threadIdx.x);
    } else {
        transpose_tile<NCD>(deps + (size_t)((z - NV)*NCD)*HWN + y*WW + xb,
                            depsH + (size_t)((z - NV)*HWN + y*WW + xb) * NCD,
                            lds, threadIdx.x);
    }
}

// ---------------------------------------------------------------------------
// Main: block = 256 threads = 4 waves = 8 pixels x 32 depths.
// Owner lane (pl, j=lane&7) computes a CLAMPED 2x2 bilinear footprint for
// depth dbase+j. Pure-roundoff fractions are snapped to exact 0/1 and the
// footprint canonicalized so a degenerate y-interp (wy==0, the case this
// dataset always hits: rot==I, ty==0 -> py==y) puts ALL weight in the A row
// -> packed B weights are integer-zero -> the 2 B-row loads per view are
// SKIPPED (wave-uniform branch on this data; generic fallback is exec-masked
// and bit-exact since skipped terms are exactly *0). Halves gather traffic.
// grid = HWN/8 = 2560 blocks.
// ---------------------------------------------------------------------------
__global__ __launch_bounds__(256) void cost_volume_k(
    const __half* __restrict__ featH,  // (V,HW,32) fp16
    const __half* __restrict__ depsH,  // (V,HW,8)  fp16
    const float* __restrict__ dvals,   // (D,HW)
    const float* __restrict__ regw,    // 40
    const float* __restrict__ pws,     // 24 (uniform -> scalar loads)
    float* __restrict__ out)
{
    __shared__ float cl [ND][9];
    __shared__ float dvl[ND][9];
    __shared__ float smax[8], sisum[8];

    const int t    = threadIdx.x;
    const int lane = t & 63;
    const int wid  = t >> 6;
    const int cg2  = lane & 3;          // feat channel group (8 ch each)
    const int dp   = (lane >> 2) & 1;   // feat depth-pair bit
    const int pl   = lane >> 3;
    const int pixg = blockIdx.x * 8 + pl;
    const int y    = pixg / WW;
    const int x    = pixg - y * WW;
    const float fx = (float)x, fy = (float)y;
    const int dbase = wid * 8;
    const int plbase = lane & 0x38;

    float RX[2], RY[2], RZ[2], T0[2], T1[2], T2[2];
    #pragma unroll
    for (int v = 0; v < 2; v++) {
        const float* q = pws + v*12;
        RX[v] = q[0]*fx + q[1]*fy + q[2];
        RY[v] = q[3]*fx + q[4]*fy + q[5];
        RZ[v] = q[6]*fx + q[7]*fy + q[8];
        T0[v] = q[9]; T1[v] = q[10]; T2[v] = q[11];
    }

    // Owner lane (pl, j=lane&7): clamped-footprint setup for depth dbase+j.
    int SWA[2], SWB[2];   // packed half2: A=(W00,W10), B=(W01,W11)
    int SO [2];           // (yb*WW+xb)*NCF
    {
        float dvv_own = dvals[(dbase + (lane & 7))*HWN + pixg];
        dvl[dbase + (lane & 7)][pl] = dvv_own;
        #pragma unroll
        for (int v = 0; v < 2; v++) {
            float pz = RZ[v]*dvv_own + T2[v];
            float iz = __builtin_amdgcn_rcpf(pz);
            float px = (RX[v]*dvv_own + T0[v]) * iz;
            float py = (RY[v]*dvv_own + T1[v]) * iz;
            float x0f = floorf(px), y0f = floorf(py);
            float wx = px - x0f, wy = py - y0f;
            // snap pure-roundoff fractions to exact 0 (canonical: weight on A row/col)
            if (wx < SNAPF)            wx = 0.f;
            else if (wx > 1.f - SNAPF) { wx = 0.f; x0f += 1.f; }
            if (wy < SNAPF)            wy = 0.f;
            else if (wy > 1.f - SNAPF) { wy = 0.f; y0f += 1.f; }
            int x0 = (int)x0f, y0 = (int)y0f;
            float omx = 1.f - wx, omy = 1.f - wy;
            int xb = min(max(x0, 0), WW-2);
            float wx0 = (x0 == xb) ? omx : ((x0 == xb-1) ? wx  : 0.f);
            float wx1 = (x0 == xb) ? wx  : ((x0 == xb+1) ? omx : 0.f);
            int yb; float wy0, wy1;
            if (wy == 0.f) {
                // degenerate y: single row y0; B row exactly zero (also at y borders)
                yb  = min(max(y0, 0), HH-1);
                wy0 = (y0 == yb) ? 1.f : 0.f;
                wy1 = 0.f;
            } else {
                yb  = min(max(y0, 0), HH-2);
                wy0 = (y0 == yb) ? omy : ((y0 == yb-1) ? wy  : 0.f);
                wy1 = (y0 == yb) ? wy  : ((y0 == yb+1) ? omy : 0.f);
            }
            __half2 hA = __floats2half2_rn(wx0*wy0, wx1*wy0);
            __half2 hB = __floats2half2_rn(wx0*wy1, wx1*wy1);
            SWA[v] = *(int*)&hA;
            SWB[v] = *(int*)&hB;
            SO[v]  = (yb*WW + xb)*NCF;
        }
    }

    #define H2OF(u, k) (((const __half2*)&(u))[k])
    // A-row 2-tap accumulate into wv[], then optional B-row 2-tap
    #define ROWA8H(u00, u10, W0p, W1p)                                         \
        { _Pragma("unroll")                                                    \
          for (int k = 0; k < 4; k++) {                                        \
            wv[k] = __hmul2(H2OF(u00,k), W0p);                                 \
            wv[k] = __hfma2(H2OF(u10,k), W1p, wv[k]);                          \
          } }
    #define ROWB8H(u01, u11, W0p, W1p)                                         \
        { _Pragma("unroll")                                                    \
          for (int k = 0; k < 4; k++) {                                        \
            wv[k] = __hfma2(H2OF(u01,k), W0p, wv[k]);                          \
            wv[k] = __hfma2(H2OF(u11,k), W1p, wv[k]);                          \
          } }
    #define ACC8H()                                                            \
        { _Pragma("unroll")                                                    \
          for (int k = 0; k < 4; k++) {                                        \
            s2[k] = __hadd2(s2[k], wv[k]);                                     \
            q2[k] = __hfma2(wv[k], wv[k], q2[k]);                              \
          } }

    // ================== FEAT PHASE ==================
    {
        const uint4 ur4 = *(const uint4*)(featH + (size_t)pixg*NCF + cg2*8);
        __half2 wca2[4], nwcb2[4];
        {
            float4 wa = *(const float4*)(regw + cg2*8);
            float4 wb = *(const float4*)(regw + cg2*8 + 4);
            wca2[0]  = __floats2half2_rn( wa.x*(1.f/3.f),  wa.y*(1.f/3.f));
            wca2[1]  = __floats2half2_rn( wa.z*(1.f/3.f),  wa.w*(1.f/3.f));
            wca2[2]  = __floats2half2_rn( wb.x*(1.f/3.f),  wb.y*(1.f/3.f));
            wca2[3]  = __floats2half2_rn( wb.z*(1.f/3.f),  wb.w*(1.f/3.f));
            nwcb2[0] = __floats2half2_rn(-wa.x*(1.f/9.f), -wa.y*(1.f/9.f));
            nwcb2[1] = __floats2half2_rn(-wa.z*(1.f/9.f), -wa.w*(1.f/9.f));
            nwcb2[2] = __floats2half2_rn(-wb.x*(1.f/9.f), -wb.y*(1.f/9.f));
            nwcb2[3] = __floats2half2_rn(-wb.z*(1.f/9.f), -wb.w*(1.f/9.f));
        }
        const __half* b1 = featH + (size_t)1*HWN*NCF + cg2*8;
        const __half* b2 = featH + (size_t)2*HWN*NCF + cg2*8;

        #pragma unroll 2
        for (int jp = 0; jp < 4; jp++) {
            const int jj  = (dp << 2) | jp;
            const int src = plbase | jj;

            // 3 shfls per view: packed weights A,B + base offset
            int aA = __shfl(SWA[0], src, 64);
            int aB = __shfl(SWB[0], src, 64);
            int oA = __shfl(SO [0], src, 64);
            int bA = __shfl(SWA[1], src, 64);
            int bB = __shfl(SWB[1], src, 64);
            int oB = __shfl(SO [1], src, 64);

            const __half* pA0 = b1 + oA;
            const __half* pB0 = b2 + oB;
            uint4 a00 = *(const uint4*)(pA0);
            uint4 a10 = *(const uint4*)(pA0 + NCF);
            uint4 c00 = *(const uint4*)(pB0);
            uint4 c10 = *(const uint4*)(pB0 + NCF);

            __half2 s2[4], q2[4], wv[4];
            #pragma unroll
            for (int k = 0; k < 4; k++) {
                __half2 r = H2OF(ur4, k);
                s2[k] = r;
                q2[k] = __hmul2(r, r);
            }
            {   // view 1
                __half2 A = *(__half2*)&aA;
                ROWA8H(a00, a10, __low2half2(A), __high2half2(A))
                if (aB) {   // B row carries weight (generic path; never on this data)
                    const __half* pA1 = pA0 + WW*NCF;
                    uint4 a01 = *(const uint4*)(pA1);
                    uint4 a11 = *(const uint4*)(pA1 + NCF);
                    __half2 Bv = *(__half2*)&aB;
                    ROWB8H(a01, a11, __low2half2(Bv), __high2half2(Bv))
                }
                ACC8H()
            }
            {   // view 2
                __half2 A = *(__half2*)&bA;
                ROWA8H(c00, c10, __low2half2(A), __high2half2(A))
                if (bB) {
                    const __half* pB1 = pB0 + WW*NCF;
                    uint4 c01 = *(const uint4*)(pB1);
                    uint4 c11 = *(const uint4*)(pB1 + NCF);
                    __half2 Bv = *(__half2*)&bB;
                    ROWB8H(c01, c11, __low2half2(Bv), __high2half2(Bv))
                }
                ACC8H()
            }

            __half2 acc = __hmul2(q2[0], wca2[0]);
            acc = __hfma2(__hmul2(s2[0], s2[0]), nwcb2[0], acc);
            #pragma unroll
            for (int k = 1; k < 4; k++) {
                acc = __hfma2(q2[k], wca2[k], acc);
                acc = __hfma2(__hmul2(s2[k], s2[k]), nwcb2[k], acc);
            }
            float2 af = __half22float2(acc);
            float part = af.x + af.y;
            part += __shfl_xor(part, 1);
            part += __shfl_xor(part, 2);
            if (cg2 == 0) cl[dbase + jj][pl] = part;
        }
    }

    // ================== DEPS PHASE ==================
    // lane = (pl<3>, ds<3>): setup in regs; B rows skipped when weight==0.
    {
        const int d = dbase + (lane & 7);
        const uint4 ur4 = *(const uint4*)(depsH + (size_t)pixg*NCD);
        __half2 wca2[4], nwcb2[4];
        {
            float4 wa = *(const float4*)(regw + NCF);
            float4 wb = *(const float4*)(regw + NCF + 4);
            wca2[0]  = __floats2half2_rn( wa.x*(1.f/3.f),  wa.y*(1.f/3.f));
            wca2[1]  = __floats2half2_rn( wa.z*(1.f/3.f),  wa.w*(1.f/3.f));
            wca2[2]  = __floats2half2_rn( wb.x*(1.f/3.f),  wb.y*(1.f/3.f));
            wca2[3]  = __floats2half2_rn( wb.z*(1.f/3.f),  wb.w*(1.f/3.f));
            nwcb2[0] = __floats2half2_rn(-wa.x*(1.f/9.f), -wa.y*(1.f/9.f));
            nwcb2[1] = __floats2half2_rn(-wa.z*(1.f/9.f), -wa.w*(1.f/9.f));
            nwcb2[2] = __floats2half2_rn(-wb.x*(1.f/9.f), -wb.y*(1.f/9.f));
            nwcb2[3] = __floats2half2_rn(-wb.z*(1.f/9.f), -wb.w*(1.f/9.f));
        }
        const __half* pA0 = depsH + (size_t)1*HWN*NCD + (SO[0] >> 2);
        const __half* pB0 = depsH + (size_t)2*HWN*NCD + (SO[1] >> 2);

        uint4 a00 = *(const uint4*)(pA0);
        uint4 a10 = *(const uint4*)(pA0 + NCD);
        uint4 c00 = *(const uint4*)(pB0);
        uint4 c10 = *(const uint4*)(pB0 + NCD);

        __half2 s2[4], q2[4], wv[4];
        #pragma unroll
        for (int k = 0; k < 4; k++) {
            __half2 r = H2OF(ur4, k);
            s2[k] = r;
            q2[k] = __hmul2(r, r);
        }
        {   // view 1
            __half2 A = *(__half2*)&SWA[0];
            ROWA8H(a00, a10, __low2half2(A), __high2half2(A))
            if (SWB[0]) {
                uint4 a01 = *(const uint4*)(pA0 + WW*NCD);
                uint4 a11 = *(const uint4*)(pA0 + WW*NCD + NCD);
                __half2 Bv = *(__half2*)&SWB[0];
                ROWB8H(a01, a11, __low2half2(Bv), __high2half2(Bv))
            }
            ACC8H()
        }
        {   // view 2
            __half2 A = *(__half2*)&SWA[1];
            ROWA8H(c00, c10, __low2half2(A), __high2half2(A))
            if (SWB[1]) {
                uint4 c01 = *(const uint4*)(pB0 + WW*NCD);
                uint4 c11 = *(const uint4*)(pB0 + WW*NCD + NCD);
                __half2 Bv = *(__half2*)&SWB[1];
                ROWB8H(c01, c11, __low2half2(Bv), __high2half2(Bv))
            }
            ACC8H()
        }

        __half2 acc = __hmul2(q2[0], wca2[0]);
        acc = __hfma2(__hmul2(s2[0], s2[0]), nwcb2[0], acc);
        #pragma unroll
        for (int k = 1; k < 4; k++) {
            acc = __hfma2(q2[k], wca2[k], acc);
            acc = __hfma2(__hmul2(s2[k], s2[k]), nwcb2[k], acc);
        }
        float2 af = __half22float2(acc);
        cl[d][pl] += af.x + af.y;   // unique (d,pl) per lane
    }
    __syncthreads();

    // ================== SOFTMAX + MOMENTS ==================
    if (t < 8) {
        const int plx  = t;
        const int pixo = blockIdx.x * 8 + plx;
        float m = -1e30f;
        #pragma unroll
        for (int d = 0; d < ND; d++) m = fmaxf(m, cl[d][plx]);
        float sum = 0.f, pd = 0.f, pd2 = 0.f;
        #pragma unroll
        for (int d = 0; d < ND; d++) {
            float e   = __expf(cl[d][plx] - m);
            float dvv = dvl[d][plx];
            sum += e;
            pd  = fmaf(e, dvv, pd);
            pd2 = fmaf(e, dvv*dvv, pd2);
        }
        float isum  = 1.f / sum;
        float depth = pd * isum;
        float sv    = pd2 * isum - depth*depth;
        float ev    = LAMBF * sqrtf(fmaxf(sv, 0.f));
        smax[plx]  = m;
        sisum[plx] = isum;
        out[pixo]       = depth;
        out[HWN + pixo] = ev;
    }
    __syncthreads();
    {
        const int plx  = t & 7;
        const int dd   = t >> 3;
        const int pixo = blockIdx.x * 8 + plx;
        out[2*HWN + dd*HWN + pixo] = __expf(cl[dd][plx] - smax[plx]) * sisum[plx];
    }
}

// ---------------------------------------------------------------------------
extern "C" void kernel_launch(void* const* d_in, const int* in_sizes, int n_in,
                              void* d_out, int out_size, void* d_ws, size_t ws_size,
                              hipStream_t stream) {
    const float* features = (const float*)d_in[0];   // (V,1,32,H,W)
    const float* deps     = (const float*)d_in[1];   // (V,1,8,H,W)
    const float* proj     = (const float*)d_in[2];   // (1,V,4,4)
    const float* dvals    = (const float*)d_in[3];   // (1,D,H,W)
    const float* regw     = (const float*)d_in[4];   // (1,40)

    float*  ws    = (float*)d_ws;
    float*  projw = ws;                              // 24 floats (64 reserved)
    __half* featH = (__half*)(ws + 64);              // 3*HW*32 halves
    __half* depsH = featH + (size_t)NV*HWN*NCF;      // 3*HW*8 halves

    dim3 tg(WW/32, HH, 2*NV);
    prep_k<<<tg, 256, 0, stream>>>(features, deps, proj, featH, depsH, projw);

    cost_volume_k<<<HWN/8, 256, 0, stream>>>(featH, depsH, dvals, regw, projw,
                                             (float*)d_out);
}